// Round 14
// baseline (183.141 us; speedup 1.0000x reference)
//
#include <hip/hip_runtime.h>

// Problem constants
#define BQ   2
#define SQ   2048
#define DIMQ 1024
#define HQ   16
#define HDQ  64
#define KQ   64
#define QKV_STRIDE (3 * DIMQ)

typedef __attribute__((ext_vector_type(8))) short short8;   // 8 bf16 (4 VGPRs)
typedef __attribute__((ext_vector_type(4))) float floatx4;  // 4 fp32 acc
typedef __attribute__((ext_vector_type(2))) float floatx2;  // packed f32 pair
typedef __attribute__((ext_vector_type(4))) unsigned int uintx4;  // 4x(2 bf16)

typedef const __attribute__((address_space(1))) unsigned short* gas_t;
typedef __attribute__((address_space(3))) unsigned short* las_t;

__device__ __forceinline__ unsigned short f2b(float f) {
    union { float f; unsigned int u; } x; x.f = f;
    unsigned int r = x.u + 0x7fffu + ((x.u >> 16) & 1u);   // RNE
    return (unsigned short)(r >> 16);
}
__device__ __forceinline__ float b2f(unsigned short u) {
    union { unsigned int u; float f; } x; x.u = ((unsigned int)u) << 16;
    return x.f;
}
__device__ __forceinline__ float u2f(unsigned int u) {
    union { unsigned int u; float f; } x; x.u = u;
    return x.f;
}

// ---------------------------------------------------------------------------
// Fused fp32 -> bf16 cast over three buffers (x, w_qkv, w_out), float4 lanes.
__global__ __launch_bounds__(256) void cast3_f32_bf16(const float* __restrict__ s0, unsigned short* __restrict__ d0, int n0,
                                                      const float* __restrict__ s1, unsigned short* __restrict__ d1, int n1,
                                                      const float* __restrict__ s2, unsigned short* __restrict__ d2, int n2) {
    int i = blockIdx.x * blockDim.x + threadIdx.x;
    const float* s; unsigned short* d;
    if (i < n0)                { s = s0; d = d0; }
    else if (i < n0 + n1)      { s = s1; d = d1; i -= n0; }
    else if (i < n0 + n1 + n2) { s = s2; d = d2; i -= n0 + n1; }
    else return;
    float4 v = ((const float4*)s)[i];
    ushort4 o;
    o.x = f2b(v.x); o.y = f2b(v.y); o.z = f2b(v.z); o.w = f2b(v.w);
    ((ushort4*)d)[i] = o;
}

// ---------------------------------------------------------------------------
// C[M,N] = A[M,K] @ B[N,K]^T + bias[N]   (A,B bf16 row-major; C fp32 or bf16)
// BMxBN tile, BK=64 (32 MFMAs between barriers), 256 threads = 4 waves
// (2x2 of BM/2 x BN/2), 16x16x32 MFMA. XOR k-chunk swizzle on the global side.
// XCD-aware chunked block swizzle (T1): lin -> (lin&7)*nwg/8 + lin>>3
// (bijective when 8 | nwg; all grids comply) so each XCD owns a contiguous
// run of row-bands -> A-panel L2 traffic / 8.
template <int BM, int BN, typename CT>
__global__ __launch_bounds__(256) void gemm_bf16_nt(const unsigned short* __restrict__ A,
                                                    const unsigned short* __restrict__ B,
                                                    const float* __restrict__ bias,
                                                    CT* __restrict__ C,
                                                    int M, int N, int K) {
    constexpr int MI = BM / 32;          // 16-row mfma tiles per wave
    constexpr int NJ = BN / 32;          // 16-col mfma tiles per wave
    __shared__ unsigned short As[BM * 64];
    __shared__ unsigned short Bs[BN * 64];

    const int tid  = threadIdx.x;
    const int lane = tid & 63;
    const int wv   = tid >> 6;            // 0..3
    const int wm   = (wv >> 1) * (BM / 2);
    const int wn   = (wv & 1) * (BN / 2);
    const int fr   = lane & 15;           // fragment row (m or n)
    const int fq   = lane >> 4;           // quad -> k segment (8 elems)

    // XCD-aware chunked swizzle of the linear block id (requires 8 | nwg).
    const int gx   = gridDim.x;
    const int nwg  = gridDim.x * gridDim.y;
    const int lin  = blockIdx.y * gridDim.x + blockIdx.x;
    const int lin2 = (lin & 7) * (nwg >> 3) + (lin >> 3);
    const int m0 = (lin2 / gx) * BM;
    const int n0 = (lin2 % gx) * BN;

    floatx4 acc[MI][NJ];
#pragma unroll
    for (int i = 0; i < MI; ++i)
#pragma unroll
        for (int j = 0; j < NJ; ++j) acc[i][j] = (floatx4)(0.f);

    const unsigned short* Ab = A + (size_t)m0 * K;
    const unsigned short* Bb = B + (size_t)n0 * K;

    for (int k0 = 0; k0 < K; k0 += 64) {
#pragma unroll
        for (int c = 0; c < (BM + BN) * 8; c += 256) {
            const int cc = c + tid;
            if (cc < BM * 8) {
                const int row = cc >> 3;
                const int kc  = ((cc & 7) ^ (row & 7)) << 3;
                __builtin_amdgcn_global_load_lds(
                    (gas_t)(Ab + (size_t)row * K + k0 + kc),
                    (las_t)&As[cc * 8], 16, 0, 0);
            } else {
                const int c2  = cc - BM * 8;
                const int row = c2 >> 3;
                const int kc  = ((c2 & 7) ^ (row & 7)) << 3;
                __builtin_amdgcn_global_load_lds(
                    (gas_t)(Bb + (size_t)row * K + k0 + kc),
                    (las_t)&Bs[c2 * 8], 16, 0, 0);
            }
        }
        __syncthreads();

#pragma unroll
        for (int ks = 0; ks < 2; ++ks) {
            short8 af[MI], bf[NJ];
#pragma unroll
            for (int i = 0; i < MI; ++i) {
                const int row = wm + i * 16 + fr;
                const int pos = (ks * 4 + fq) ^ (row & 7);
                af[i] = *(const short8*)&As[row * 64 + pos * 8];
            }
#pragma unroll
            for (int j = 0; j < NJ; ++j) {
                const int row = wn + j * 16 + fr;
                const int pos = (ks * 4 + fq) ^ (row & 7);
                bf[j] = *(const short8*)&Bs[row * 64 + pos * 8];
            }
#pragma unroll
            for (int i = 0; i < MI; ++i)
#pragma unroll
                for (int j = 0; j < NJ; ++j)
                    acc[i][j] = __builtin_amdgcn_mfma_f32_16x16x32_bf16(af[i], bf[j], acc[i][j], 0, 0, 0);
        }
        __syncthreads();
    }

    // Epilogue. D mapping: col = lane&15 (=fr), row = (lane>>4)*4 + reg (=fq*4+r)
    float bv[NJ];
#pragma unroll
    for (int j = 0; j < NJ; ++j) bv[j] = bias[n0 + wn + j * 16 + fr];
#pragma unroll
    for (int i = 0; i < MI; ++i) {
#pragma unroll
        for (int r = 0; r < 4; ++r) {
            const size_t row = (size_t)(m0 + wm + i * 16 + fq * 4 + r);
#pragma unroll
            for (int j = 0; j < NJ; ++j) {
                const float v = acc[i][j][r] + bv[j];
                if constexpr (sizeof(CT) == 2)
                    C[row * N + n0 + wn + j * 16 + fr] = (CT)f2b(v);
                else
                    C[row * N + n0 + wn + j * 16 + fr] = (CT)v;
            }
        }
    }
}

// ---------------------------------------------------------------------------
// R12/R14 attention (best-total config): scalar-pipe addressing + defer-max
// + hw bf16 dot + pk-f32 PV, 4-slot prefetch.  Prefetch-depth axis closed:
// 2->4 null (R11), 4->8 null with occupancy cost (R15).
// Route indices are wave-uniform -> hoisted to SGPRs via readfirstlane(g) +
// full unroll; per-j K/V loads are global_load_dwordx4 with scalar base.
// One block per (b,q); 256 threads; thread t: j-group g = t>>7 (j=2*jj+g),
// head h = (t&127)>>3, dims d0 = (t&7)*8 (16 B).
// qkv: bf16 [B, S, 3, H, HD]. out: bf16 [B, S, H*HD].
__global__ __launch_bounds__(256) void attn_kernel(const unsigned short* __restrict__ qkv,
                                                   const int* __restrict__ routes,
                                                   unsigned short* __restrict__ out) {
    __shared__ float m_s[128], l_s[128];
    __shared__ float o_part[8][128];

    const int t  = threadIdx.x;           // 0..255
    const int id = blockIdx.x;
    // XCD-contiguity swizzle: same XCD (id%8) gets a contiguous bq range.
    const int bq = (id & 7) * 512 + (id >> 3);
    const int b  = bq >> 11;
    const int q  = bq & 2047;

    const int g  = t >> 7;                // j-group: 0 or 1
    const int th = t & 127;
    const int h  = th >> 3;               // head
    const int d0 = (t & 7) * 8;           // dim offset within head

    // Wave-uniform j-group for scalar addressing (readfirstlane hoists the
    // threadIdx-derived value into an SGPR so uniformity analysis succeeds).
    const int gs = __builtin_amdgcn_readfirstlane(g);

    // All 32 route indices for this wave -> SGPRs (uniform s_loads).
    int rr[32];
#pragma unroll
    for (int i = 0; i < 32; ++i) rr[i] = routes[q * KQ + i * 2 + gs];

    // q stays PACKED bf16 (4 uints = 8 elems); scale applied in exp2 arg.
    const uintx4 qp = *(const uintx4*)&qkv[((size_t)bq * 3) * DIMQ + h * HDQ + d0];

    // Uniform K/V row bases (scalar); per-lane element offset applied at load.
    const unsigned short* baseKu = qkv + ((size_t)b * SQ * 3 + 1) * DIMQ;
    const unsigned short* baseVu = qkv + ((size_t)b * SQ * 3 + 2) * DIMQ;
    const int laneoff = h * HDQ + d0;

    const float C = 0.18033688011112042f;   // SCALE * log2(e)
    float m = -1e30f, l = 0.f;
    float mC = 1e30f;                        // -m*C (cached for pe FMA)
    float m44 = -1e30f + 44.f;               // m+44 (cached for defer check)
    floatx2 o2[4];
#pragma unroll
    for (int i = 0; i < 4; ++i) o2[i] = (floatx2)(0.f);

    // Prefetch pipeline: 4 slots, loads for iteration jj+4 issued during jj.
    uintx4 kb[4], vb[4];
#pragma unroll
    for (int i = 0; i < 4; ++i) {
        const unsigned short* kp = baseKu + (size_t)rr[i] * QKV_STRIDE;
        const unsigned short* vp = baseVu + (size_t)rr[i] * QKV_STRIDE;
        kb[i] = *(const uintx4*)(kp + laneoff);
        vb[i] = *(const uintx4*)(vp + laneoff);
    }

#pragma unroll
    for (int jj = 0; jj < 32; ++jj) {
        const int slot = jj & 3;
        const uintx4 k4 = kb[slot];
        const uintx4 v4 = vb[slot];
        if (jj + 4 < 32) {
            const unsigned short* kp = baseKu + (size_t)rr[jj + 4] * QKV_STRIDE;
            const unsigned short* vp = baseVu + (size_t)rr[jj + 4] * QKV_STRIDE;
            kb[slot] = *(const uintx4*)(kp + laneoff);
            vb[slot] = *(const uintx4*)(vp + laneoff);
        }
        // QK dot: 4x v_dot2_f32_bf16 on packed bf16 pairs (no unpack).
        float p = 0.f;
#pragma unroll
        for (int i = 0; i < 4; ++i)
            asm("v_dot2_f32_bf16 %0, %1, %2, %0" : "+v"(p) : "v"(qp[i]), "v"(k4[i]));
        p += __shfl_xor(p, 1, 64);
        p += __shfl_xor(p, 2, 64);
        p += __shfl_xor(p, 4, 64);
        // Defer-max: rescale only when some lane's raw score jumps past m+44
        // (44 raw units * C = ~8 in exp2 domain -> pe <= 2^8).
        if (__any(p > m44)) {
            const float mn = fmaxf(m, p);       // per-lane guard -> exact
            const float al = exp2f((m - mn) * C);
            l *= al;
            const floatx2 al2 = { al, al };
#pragma unroll
            for (int i = 0; i < 4; ++i) o2[i] *= al2;
            m = mn;
            mC = -mn * C;
            m44 = mn + 44.f;
        }
        const float pe = exp2f(__builtin_fmaf(p, C, mC));   // <= 2^8
        l += pe;
        // PV: unpack bf16 pair (shift + and) then packed f32 FMA.
        const floatx2 pe2 = { pe, pe };
#pragma unroll
        for (int i = 0; i < 4; ++i) {
            const unsigned int u = v4[i];
            floatx2 vv;
            vv.x = u2f(u << 16);
            vv.y = u2f(u & 0xffff0000u);
            o2[i] += pe2 * vv;
        }
    }

    // Merge the two j-groups (softmax state merge, exp2 domain), then store.
    if (g == 1) {
        m_s[th] = m; l_s[th] = l;
#pragma unroll
        for (int i = 0; i < 4; ++i) {
            o_part[2 * i][th]     = o2[i].x;
            o_part[2 * i + 1][th] = o2[i].y;
        }
    }
    __syncthreads();
    if (g == 0) {
        const float m1 = m_s[th], l1m = l_s[th];
        const float mm = fmaxf(m, m1);
        const float a0 = exp2f((m - mm) * C);
        const float a1 = exp2f((m1 - mm) * C);
        const float inv = 1.0f / (l * a0 + l1m * a1);
        float oo[8];
#pragma unroll
        for (int i = 0; i < 4; ++i) {
            oo[2 * i]     = (o2[i].x * a0 + o_part[2 * i][th] * a1) * inv;
            oo[2 * i + 1] = (o2[i].y * a0 + o_part[2 * i + 1][th] * a1) * inv;
        }
        ushort4 lo, hi;
        lo.x = f2b(oo[0]); lo.y = f2b(oo[1]); lo.z = f2b(oo[2]); lo.w = f2b(oo[3]);
        hi.x = f2b(oo[4]); hi.y = f2b(oo[5]); hi.z = f2b(oo[6]); hi.w = f2b(oo[7]);
        ushort4* dst = (ushort4*)&out[(size_t)bq * DIMQ + h * HDQ + d0];
        dst[0] = lo; dst[1] = hi;
    }
}

// ---------------------------------------------------------------------------
extern "C" void kernel_launch(void* const* d_in, const int* in_sizes, int n_in,
                              void* d_out, int out_size, void* d_ws, size_t ws_size,
                              hipStream_t stream) {
    const float* x      = (const float*)d_in[0];
    const float* w_qkv  = (const float*)d_in[1];
    const float* b_qkv  = (const float*)d_in[2];
    const float* w_out  = (const float*)d_in[3];
    const float* b_out  = (const float*)d_in[4];
    const int*   routes = (const int*)d_in[5];
    float* out = (float*)d_out;

    // ws layout (bytes): [0,24M) qkv bf16 | [24M,..) xb / attnb (aliased)
    //                    then w_qkv_bf16, w_out_bf16
    char* ws = (char*)d_ws;
    unsigned short* qkvb  = (unsigned short*)ws;                      // 24 MB
    unsigned short* xb    = (unsigned short*)(ws + 25165824);         // 8.4 MB
    unsigned short* attnb = xb;                                       // aliased
    unsigned short* wqb   = (unsigned short*)(ws + 33554432);         // 6.3 MB
    unsigned short* wob   = (unsigned short*)(ws + 39845888);         // 2.1 MB

    const int M = BQ * SQ;   // 4096
    dim3 blk(256);

    // Fused casts (x, w_qkv, w_out), float4 per thread
    {
        const int n0 = M * DIMQ / 4, n1 = 3 * DIMQ * DIMQ / 4, n2 = DIMQ * DIMQ / 4;
        cast3_f32_bf16<<<(n0 + n1 + n2 + 255) / 256, blk, 0, stream>>>(
            x, xb, n0, w_qkv, wqb, n1, w_out, wob, n2);
    }

    // 1) QKV projection -> bf16 qkv [B,S,3,H,HD]  (768 blocks, 8|768: T1 ok)
    gemm_bf16_nt<128, 128, unsigned short><<<dim3(3 * DIMQ / 128, M / 128), blk, 0, stream>>>(
        xb, wqb, b_qkv, qkvb, M, 3 * DIMQ, DIMQ);

    // 2) Routed attention: scalar-pipe addressing + defer-max + hw dot
    attn_kernel<<<BQ * SQ, blk, 0, stream>>>(qkvb, routes, attnb);

    // 3) Output projection -> fp32, 128x128 tiles (256 blocks, 8|256: T1 ok)
    //    Tile ladder (m92/m103): 128^2 = 912 TF vs 64-wide ~ 343-550 TF.
    gemm_bf16_nt<128, 128, float><<<dim3(DIMQ / 128, M / 128), blk, 0, stream>>>(
        attnb, wob, b_out, out, M, DIMQ, DIMQ);
}

// Round 15
// 176.533 us; speedup vs baseline: 1.0374x; 1.0374x over previous
//
#include <hip/hip_runtime.h>

// Problem constants
#define BQ   2
#define SQ   2048
#define DIMQ 1024
#define HQ   16
#define HDQ  64
#define KQ   64
#define QKV_STRIDE (3 * DIMQ)

typedef __attribute__((ext_vector_type(8))) short short8;   // 8 bf16 (4 VGPRs)
typedef __attribute__((ext_vector_type(4))) float floatx4;  // 4 fp32 acc
typedef __attribute__((ext_vector_type(2))) float floatx2;  // packed f32 pair
typedef __attribute__((ext_vector_type(4))) unsigned int uintx4;  // 4x(2 bf16)

typedef const __attribute__((address_space(1))) unsigned short* gas_t;
typedef __attribute__((address_space(3))) unsigned short* las_t;

__device__ __forceinline__ unsigned short f2b(float f) {
    union { float f; unsigned int u; } x; x.f = f;
    unsigned int r = x.u + 0x7fffu + ((x.u >> 16) & 1u);   // RNE
    return (unsigned short)(r >> 16);
}
__device__ __forceinline__ float b2f(unsigned short u) {
    union { unsigned int u; float f; } x; x.u = ((unsigned int)u) << 16;
    return x.f;
}
__device__ __forceinline__ float u2f(unsigned int u) {
    union { unsigned int u; float f; } x; x.u = u;
    return x.f;
}

// ---------------------------------------------------------------------------
// Fused fp32 -> bf16 cast over three buffers (x, w_qkv, w_out), float4 lanes.
__global__ __launch_bounds__(256) void cast3_f32_bf16(const float* __restrict__ s0, unsigned short* __restrict__ d0, int n0,
                                                      const float* __restrict__ s1, unsigned short* __restrict__ d1, int n1,
                                                      const float* __restrict__ s2, unsigned short* __restrict__ d2, int n2) {
    int i = blockIdx.x * blockDim.x + threadIdx.x;
    const float* s; unsigned short* d;
    if (i < n0)                { s = s0; d = d0; }
    else if (i < n0 + n1)      { s = s1; d = d1; i -= n0; }
    else if (i < n0 + n1 + n2) { s = s2; d = d2; i -= n0 + n1; }
    else return;
    float4 v = ((const float4*)s)[i];
    ushort4 o;
    o.x = f2b(v.x); o.y = f2b(v.y); o.z = f2b(v.z); o.w = f2b(v.w);
    ((ushort4*)d)[i] = o;
}

// ---------------------------------------------------------------------------
// C[M,N] = A[M,K] @ B[N,K]^T + bias[N]   (A,B bf16 row-major; C fp32 or bf16)
// BMxBN tile, BK=64 (32 MFMAs between barriers), 256 threads = 4 waves
// (2x2 of BM/2 x BN/2), 16x16x32 MFMA. XOR k-chunk swizzle on the global side.
// XCD-aware chunked block swizzle (T1): lin -> (lin&7)*nwg/8 + lin>>3
// (bijective when 8 | nwg; all grids comply) so each XCD owns a contiguous
// run of row-bands -> A-panel L2 traffic / 8.
// NOTE (R16 lesson): tile choice must keep >= 2 blocks/CU co-resident; the
// 2-barrier K-loop relies on cross-block overlap to hide its barrier drain.
// GEMM2 at 128x128 (256 blocks = 1/CU) regressed 7.5us vs 128x64 (512 = 2/CU).
template <int BM, int BN, typename CT>
__global__ __launch_bounds__(256) void gemm_bf16_nt(const unsigned short* __restrict__ A,
                                                    const unsigned short* __restrict__ B,
                                                    const float* __restrict__ bias,
                                                    CT* __restrict__ C,
                                                    int M, int N, int K) {
    constexpr int MI = BM / 32;          // 16-row mfma tiles per wave
    constexpr int NJ = BN / 32;          // 16-col mfma tiles per wave
    __shared__ unsigned short As[BM * 64];
    __shared__ unsigned short Bs[BN * 64];

    const int tid  = threadIdx.x;
    const int lane = tid & 63;
    const int wv   = tid >> 6;            // 0..3
    const int wm   = (wv >> 1) * (BM / 2);
    const int wn   = (wv & 1) * (BN / 2);
    const int fr   = lane & 15;           // fragment row (m or n)
    const int fq   = lane >> 4;           // quad -> k segment (8 elems)

    // XCD-aware chunked swizzle of the linear block id (requires 8 | nwg).
    const int gx   = gridDim.x;
    const int nwg  = gridDim.x * gridDim.y;
    const int lin  = blockIdx.y * gridDim.x + blockIdx.x;
    const int lin2 = (lin & 7) * (nwg >> 3) + (lin >> 3);
    const int m0 = (lin2 / gx) * BM;
    const int n0 = (lin2 % gx) * BN;

    floatx4 acc[MI][NJ];
#pragma unroll
    for (int i = 0; i < MI; ++i)
#pragma unroll
        for (int j = 0; j < NJ; ++j) acc[i][j] = (floatx4)(0.f);

    const unsigned short* Ab = A + (size_t)m0 * K;
    const unsigned short* Bb = B + (size_t)n0 * K;

    for (int k0 = 0; k0 < K; k0 += 64) {
#pragma unroll
        for (int c = 0; c < (BM + BN) * 8; c += 256) {
            const int cc = c + tid;
            if (cc < BM * 8) {
                const int row = cc >> 3;
                const int kc  = ((cc & 7) ^ (row & 7)) << 3;
                __builtin_amdgcn_global_load_lds(
                    (gas_t)(Ab + (size_t)row * K + k0 + kc),
                    (las_t)&As[cc * 8], 16, 0, 0);
            } else {
                const int c2  = cc - BM * 8;
                const int row = c2 >> 3;
                const int kc  = ((c2 & 7) ^ (row & 7)) << 3;
                __builtin_amdgcn_global_load_lds(
                    (gas_t)(Bb + (size_t)row * K + k0 + kc),
                    (las_t)&Bs[c2 * 8], 16, 0, 0);
            }
        }
        __syncthreads();

#pragma unroll
        for (int ks = 0; ks < 2; ++ks) {
            short8 af[MI], bf[NJ];
#pragma unroll
            for (int i = 0; i < MI; ++i) {
                const int row = wm + i * 16 + fr;
                const int pos = (ks * 4 + fq) ^ (row & 7);
                af[i] = *(const short8*)&As[row * 64 + pos * 8];
            }
#pragma unroll
            for (int j = 0; j < NJ; ++j) {
                const int row = wn + j * 16 + fr;
                const int pos = (ks * 4 + fq) ^ (row & 7);
                bf[j] = *(const short8*)&Bs[row * 64 + pos * 8];
            }
#pragma unroll
            for (int i = 0; i < MI; ++i)
#pragma unroll
                for (int j = 0; j < NJ; ++j)
                    acc[i][j] = __builtin_amdgcn_mfma_f32_16x16x32_bf16(af[i], bf[j], acc[i][j], 0, 0, 0);
        }
        __syncthreads();
    }

    // Epilogue. D mapping: col = lane&15 (=fr), row = (lane>>4)*4 + reg (=fq*4+r)
    float bv[NJ];
#pragma unroll
    for (int j = 0; j < NJ; ++j) bv[j] = bias[n0 + wn + j * 16 + fr];
#pragma unroll
    for (int i = 0; i < MI; ++i) {
#pragma unroll
        for (int r = 0; r < 4; ++r) {
            const size_t row = (size_t)(m0 + wm + i * 16 + fq * 4 + r);
#pragma unroll
            for (int j = 0; j < NJ; ++j) {
                const float v = acc[i][j][r] + bv[j];
                if constexpr (sizeof(CT) == 2)
                    C[row * N + n0 + wn + j * 16 + fr] = (CT)f2b(v);
                else
                    C[row * N + n0 + wn + j * 16 + fr] = (CT)v;
            }
        }
    }
}

// ---------------------------------------------------------------------------
// R12/R14 attention (best-total config): scalar-pipe addressing + defer-max
// + hw bf16 dot + pk-f32 PV, 4-slot prefetch.  Closed axes: prefetch depth
// (2->4 null R11, 4->8 null+occupancy-cost R15), reduce geometry (R10/R13
// correctness failures), LDS staging (R7 regression).
// Route indices are wave-uniform -> hoisted to SGPRs via readfirstlane(g) +
// full unroll; per-j K/V loads are global_load_dwordx4 with scalar base.
// One block per (b,q); 256 threads; thread t: j-group g = t>>7 (j=2*jj+g),
// head h = (t&127)>>3, dims d0 = (t&7)*8 (16 B).
// qkv: bf16 [B, S, 3, H, HD]. out: bf16 [B, S, H*HD].
__global__ __launch_bounds__(256) void attn_kernel(const unsigned short* __restrict__ qkv,
                                                   const int* __restrict__ routes,
                                                   unsigned short* __restrict__ out) {
    __shared__ float m_s[128], l_s[128];
    __shared__ float o_part[8][128];

    const int t  = threadIdx.x;           // 0..255
    const int id = blockIdx.x;
    // XCD-contiguity swizzle: same XCD (id%8) gets a contiguous bq range.
    const int bq = (id & 7) * 512 + (id >> 3);
    const int b  = bq >> 11;
    const int q  = bq & 2047;

    const int g  = t >> 7;                // j-group: 0 or 1
    const int th = t & 127;
    const int h  = th >> 3;               // head
    const int d0 = (t & 7) * 8;           // dim offset within head

    // Wave-uniform j-group for scalar addressing (readfirstlane hoists the
    // threadIdx-derived value into an SGPR so uniformity analysis succeeds).
    const int gs = __builtin_amdgcn_readfirstlane(g);

    // All 32 route indices for this wave -> SGPRs (uniform s_loads).
    int rr[32];
#pragma unroll
    for (int i = 0; i < 32; ++i) rr[i] = routes[q * KQ + i * 2 + gs];

    // q stays PACKED bf16 (4 uints = 8 elems); scale applied in exp2 arg.
    const uintx4 qp = *(const uintx4*)&qkv[((size_t)bq * 3) * DIMQ + h * HDQ + d0];

    // Uniform K/V row bases (scalar); per-lane element offset applied at load.
    const unsigned short* baseKu = qkv + ((size_t)b * SQ * 3 + 1) * DIMQ;
    const unsigned short* baseVu = qkv + ((size_t)b * SQ * 3 + 2) * DIMQ;
    const int laneoff = h * HDQ + d0;

    const float C = 0.18033688011112042f;   // SCALE * log2(e)
    float m = -1e30f, l = 0.f;
    float mC = 1e30f;                        // -m*C (cached for pe FMA)
    float m44 = -1e30f + 44.f;               // m+44 (cached for defer check)
    floatx2 o2[4];
#pragma unroll
    for (int i = 0; i < 4; ++i) o2[i] = (floatx2)(0.f);

    // Prefetch pipeline: 4 slots, loads for iteration jj+4 issued during jj.
    uintx4 kb[4], vb[4];
#pragma unroll
    for (int i = 0; i < 4; ++i) {
        const unsigned short* kp = baseKu + (size_t)rr[i] * QKV_STRIDE;
        const unsigned short* vp = baseVu + (size_t)rr[i] * QKV_STRIDE;
        kb[i] = *(const uintx4*)(kp + laneoff);
        vb[i] = *(const uintx4*)(vp + laneoff);
    }

#pragma unroll
    for (int jj = 0; jj < 32; ++jj) {
        const int slot = jj & 3;
        const uintx4 k4 = kb[slot];
        const uintx4 v4 = vb[slot];
        if (jj + 4 < 32) {
            const unsigned short* kp = baseKu + (size_t)rr[jj + 4] * QKV_STRIDE;
            const unsigned short* vp = baseVu + (size_t)rr[jj + 4] * QKV_STRIDE;
            kb[slot] = *(const uintx4*)(kp + laneoff);
            vb[slot] = *(const uintx4*)(vp + laneoff);
        }
        // QK dot: 4x v_dot2_f32_bf16 on packed bf16 pairs (no unpack).
        float p = 0.f;
#pragma unroll
        for (int i = 0; i < 4; ++i)
            asm("v_dot2_f32_bf16 %0, %1, %2, %0" : "+v"(p) : "v"(qp[i]), "v"(k4[i]));
        p += __shfl_xor(p, 1, 64);
        p += __shfl_xor(p, 2, 64);
        p += __shfl_xor(p, 4, 64);
        // Defer-max: rescale only when some lane's raw score jumps past m+44
        // (44 raw units * C = ~8 in exp2 domain -> pe <= 2^8).
        if (__any(p > m44)) {
            const float mn = fmaxf(m, p);       // per-lane guard -> exact
            const float al = exp2f((m - mn) * C);
            l *= al;
            const floatx2 al2 = { al, al };
#pragma unroll
            for (int i = 0; i < 4; ++i) o2[i] *= al2;
            m = mn;
            mC = -mn * C;
            m44 = mn + 44.f;
        }
        const float pe = exp2f(__builtin_fmaf(p, C, mC));   // <= 2^8
        l += pe;
        // PV: unpack bf16 pair (shift + and) then packed f32 FMA.
        const floatx2 pe2 = { pe, pe };
#pragma unroll
        for (int i = 0; i < 4; ++i) {
            const unsigned int u = v4[i];
            floatx2 vv;
            vv.x = u2f(u << 16);
            vv.y = u2f(u & 0xffff0000u);
            o2[i] += pe2 * vv;
        }
    }

    // Merge the two j-groups (softmax state merge, exp2 domain), then store.
    if (g == 1) {
        m_s[th] = m; l_s[th] = l;
#pragma unroll
        for (int i = 0; i < 4; ++i) {
            o_part[2 * i][th]     = o2[i].x;
            o_part[2 * i + 1][th] = o2[i].y;
        }
    }
    __syncthreads();
    if (g == 0) {
        const float m1 = m_s[th], l1m = l_s[th];
        const float mm = fmaxf(m, m1);
        const float a0 = exp2f((m - mm) * C);
        const float a1 = exp2f((m1 - mm) * C);
        const float inv = 1.0f / (l * a0 + l1m * a1);
        float oo[8];
#pragma unroll
        for (int i = 0; i < 4; ++i) {
            oo[2 * i]     = (o2[i].x * a0 + o_part[2 * i][th] * a1) * inv;
            oo[2 * i + 1] = (o2[i].y * a0 + o_part[2 * i + 1][th] * a1) * inv;
        }
        ushort4 lo, hi;
        lo.x = f2b(oo[0]); lo.y = f2b(oo[1]); lo.z = f2b(oo[2]); lo.w = f2b(oo[3]);
        hi.x = f2b(oo[4]); hi.y = f2b(oo[5]); hi.z = f2b(oo[6]); hi.w = f2b(oo[7]);
        ushort4* dst = (ushort4*)&out[(size_t)bq * DIMQ + h * HDQ + d0];
        dst[0] = lo; dst[1] = hi;
    }
}

// ---------------------------------------------------------------------------
extern "C" void kernel_launch(void* const* d_in, const int* in_sizes, int n_in,
                              void* d_out, int out_size, void* d_ws, size_t ws_size,
                              hipStream_t stream) {
    const float* x      = (const float*)d_in[0];
    const float* w_qkv  = (const float*)d_in[1];
    const float* b_qkv  = (const float*)d_in[2];
    const float* w_out  = (const float*)d_in[3];
    const float* b_out  = (const float*)d_in[4];
    const int*   routes = (const int*)d_in[5];
    float* out = (float*)d_out;

    // ws layout (bytes): [0,24M) qkv bf16 | [24M,..) xb / attnb (aliased)
    //                    then w_qkv_bf16, w_out_bf16
    char* ws = (char*)d_ws;
    unsigned short* qkvb  = (unsigned short*)ws;                      // 24 MB
    unsigned short* xb    = (unsigned short*)(ws + 25165824);         // 8.4 MB
    unsigned short* attnb = xb;                                       // aliased
    unsigned short* wqb   = (unsigned short*)(ws + 33554432);         // 6.3 MB
    unsigned short* wob   = (unsigned short*)(ws + 39845888);         // 2.1 MB

    const int M = BQ * SQ;   // 4096
    dim3 blk(256);

    // Fused casts (x, w_qkv, w_out), float4 per thread
    {
        const int n0 = M * DIMQ / 4, n1 = 3 * DIMQ * DIMQ / 4, n2 = DIMQ * DIMQ / 4;
        cast3_f32_bf16<<<(n0 + n1 + n2 + 255) / 256, blk, 0, stream>>>(
            x, xb, n0, w_qkv, wqb, n1, w_out, wob, n2);
    }

    // 1) QKV projection -> bf16 qkv [B,S,3,H,HD]  (768 blocks = 3/CU, T1 ok)
    gemm_bf16_nt<128, 128, unsigned short><<<dim3(3 * DIMQ / 128, M / 128), blk, 0, stream>>>(
        xb, wqb, b_qkv, qkvb, M, 3 * DIMQ, DIMQ);

    // 2) Routed attention: scalar-pipe addressing + defer-max + hw dot
    attn_kernel<<<BQ * SQ, blk, 0, stream>>>(qkvb, routes, attnb);

    // 3) Output projection -> fp32 final output (512 blocks = 2/CU, T1 ok)
    gemm_bf16_nt<128, 64, float><<<dim3(DIMQ / 64, M / 128), blk, 0, stream>>>(
        attnb, wob, b_out, out, M, DIMQ, DIMQ);
}

// Round 17
// 175.527 us; speedup vs baseline: 1.0434x; 1.0057x over previous
//
#include <hip/hip_runtime.h>

// Problem constants
#define BQ   2
#define SQ   2048
#define DIMQ 1024
#define HQ   16
#define HDQ  64
#define KQ   64
#define QKV_STRIDE (3 * DIMQ)

typedef __attribute__((ext_vector_type(8))) short short8;   // 8 bf16 (4 VGPRs)
typedef __attribute__((ext_vector_type(4))) float floatx4;  // 4 fp32 acc
typedef __attribute__((ext_vector_type(2))) float floatx2;  // packed f32 pair
typedef __attribute__((ext_vector_type(4))) unsigned int uintx4;  // 4x(2 bf16)

typedef const __attribute__((address_space(1))) unsigned short* gas_t;
typedef __attribute__((address_space(3))) unsigned short* las_t;

__device__ __forceinline__ unsigned short f2b(float f) {
    union { float f; unsigned int u; } x; x.f = f;
    unsigned int r = x.u + 0x7fffu + ((x.u >> 16) & 1u);   // RNE
    return (unsigned short)(r >> 16);
}
__device__ __forceinline__ float b2f(unsigned short u) {
    union { unsigned int u; float f; } x; x.u = ((unsigned int)u) << 16;
    return x.f;
}
__device__ __forceinline__ float u2f(unsigned int u) {
    union { unsigned int u; float f; } x; x.u = u;
    return x.f;
}

// ---------------------------------------------------------------------------
// Fused fp32 -> bf16 cast over three buffers (x, w_qkv, w_out), float4 lanes.
__global__ __launch_bounds__(256) void cast3_f32_bf16(const float* __restrict__ s0, unsigned short* __restrict__ d0, int n0,
                                                      const float* __restrict__ s1, unsigned short* __restrict__ d1, int n1,
                                                      const float* __restrict__ s2, unsigned short* __restrict__ d2, int n2) {
    int i = blockIdx.x * blockDim.x + threadIdx.x;
    const float* s; unsigned short* d;
    if (i < n0)                { s = s0; d = d0; }
    else if (i < n0 + n1)      { s = s1; d = d1; i -= n0; }
    else if (i < n0 + n1 + n2) { s = s2; d = d2; i -= n0 + n1; }
    else return;
    float4 v = ((const float4*)s)[i];
    ushort4 o;
    o.x = f2b(v.x); o.y = f2b(v.y); o.z = f2b(v.z); o.w = f2b(v.w);
    ((ushort4*)d)[i] = o;
}

// ---------------------------------------------------------------------------
// C[M,N] = A[M,K] @ B[N,K]^T + bias[N]   (A,B bf16 row-major; C fp32 or bf16)
// BMxBN tile, BK=64 (32 MFMAs between barriers), 256 threads = 4 waves
// (2x2 of BM/2 x BN/2), 16x16x32 MFMA. XOR k-chunk swizzle on the global side.
// XCD-aware chunked block swizzle (T1): lin -> (lin&7)*nwg/8 + lin>>3
// (bijective when 8 | nwg; all grids comply) so each XCD owns a contiguous
// run of row-bands -> A-panel L2 traffic / 8.
// NOTE (R16 lesson): tile choice must keep >= 2 blocks/CU co-resident; the
// 2-barrier K-loop relies on cross-block overlap to hide its barrier drain.
// GEMM2 at 128x128 (256 blocks = 1/CU) regressed 7.5us vs 128x64 (512 = 2/CU).
template <int BM, int BN, typename CT>
__global__ __launch_bounds__(256) void gemm_bf16_nt(const unsigned short* __restrict__ A,
                                                    const unsigned short* __restrict__ B,
                                                    const float* __restrict__ bias,
                                                    CT* __restrict__ C,
                                                    int M, int N, int K) {
    constexpr int MI = BM / 32;          // 16-row mfma tiles per wave
    constexpr int NJ = BN / 32;          // 16-col mfma tiles per wave
    __shared__ unsigned short As[BM * 64];
    __shared__ unsigned short Bs[BN * 64];

    const int tid  = threadIdx.x;
    const int lane = tid & 63;
    const int wv   = tid >> 6;            // 0..3
    const int wm   = (wv >> 1) * (BM / 2);
    const int wn   = (wv & 1) * (BN / 2);
    const int fr   = lane & 15;           // fragment row (m or n)
    const int fq   = lane >> 4;           // quad -> k segment (8 elems)

    // XCD-aware chunked swizzle of the linear block id (requires 8 | nwg).
    const int gx   = gridDim.x;
    const int nwg  = gridDim.x * gridDim.y;
    const int lin  = blockIdx.y * gridDim.x + blockIdx.x;
    const int lin2 = (lin & 7) * (nwg >> 3) + (lin >> 3);
    const int m0 = (lin2 / gx) * BM;
    const int n0 = (lin2 % gx) * BN;

    floatx4 acc[MI][NJ];
#pragma unroll
    for (int i = 0; i < MI; ++i)
#pragma unroll
        for (int j = 0; j < NJ; ++j) acc[i][j] = (floatx4)(0.f);

    const unsigned short* Ab = A + (size_t)m0 * K;
    const unsigned short* Bb = B + (size_t)n0 * K;

    for (int k0 = 0; k0 < K; k0 += 64) {
#pragma unroll
        for (int c = 0; c < (BM + BN) * 8; c += 256) {
            const int cc = c + tid;
            if (cc < BM * 8) {
                const int row = cc >> 3;
                const int kc  = ((cc & 7) ^ (row & 7)) << 3;
                __builtin_amdgcn_global_load_lds(
                    (gas_t)(Ab + (size_t)row * K + k0 + kc),
                    (las_t)&As[cc * 8], 16, 0, 0);
            } else {
                const int c2  = cc - BM * 8;
                const int row = c2 >> 3;
                const int kc  = ((c2 & 7) ^ (row & 7)) << 3;
                __builtin_amdgcn_global_load_lds(
                    (gas_t)(Bb + (size_t)row * K + k0 + kc),
                    (las_t)&Bs[c2 * 8], 16, 0, 0);
            }
        }
        __syncthreads();

#pragma unroll
        for (int ks = 0; ks < 2; ++ks) {
            short8 af[MI], bf[NJ];
#pragma unroll
            for (int i = 0; i < MI; ++i) {
                const int row = wm + i * 16 + fr;
                const int pos = (ks * 4 + fq) ^ (row & 7);
                af[i] = *(const short8*)&As[row * 64 + pos * 8];
            }
#pragma unroll
            for (int j = 0; j < NJ; ++j) {
                const int row = wn + j * 16 + fr;
                const int pos = (ks * 4 + fq) ^ (row & 7);
                bf[j] = *(const short8*)&Bs[row * 64 + pos * 8];
            }
#pragma unroll
            for (int i = 0; i < MI; ++i)
#pragma unroll
                for (int j = 0; j < NJ; ++j)
                    acc[i][j] = __builtin_amdgcn_mfma_f32_16x16x32_bf16(af[i], bf[j], acc[i][j], 0, 0, 0);
        }
        __syncthreads();
    }

    // Epilogue. D mapping: col = lane&15 (=fr), row = (lane>>4)*4 + reg (=fq*4+r)
    float bv[NJ];
#pragma unroll
    for (int j = 0; j < NJ; ++j) bv[j] = bias[n0 + wn + j * 16 + fr];
#pragma unroll
    for (int i = 0; i < MI; ++i) {
#pragma unroll
        for (int r = 0; r < 4; ++r) {
            const size_t row = (size_t)(m0 + wm + i * 16 + fq * 4 + r);
#pragma unroll
            for (int j = 0; j < NJ; ++j) {
                const float v = acc[i][j][r] + bv[j];
                if constexpr (sizeof(CT) == 2)
                    C[row * N + n0 + wn + j * 16 + fr] = (CT)f2b(v);
                else
                    C[row * N + n0 + wn + j * 16 + fr] = (CT)v;
            }
        }
    }
}

// ---------------------------------------------------------------------------
// R12/R14/R17 attention (confirmed best, passed twice at 175.6/176.5 us):
// scalar-pipe addressing + defer-max + hw bf16 dot + pk-f32 PV, 4-slot
// prefetch, __shfl_xor reduce (the only correctness-proven lane reduce on
// this HW; DPP, 4-lane regeometry, and ds_swizzle all failed refcheck).
// Closed axes: prefetch depth (R11/R15 nulls), reduce geometry (R10/R13),
// cross-lane primitives (R10/R13/R18), LDS staging (R7), GEMM2 tile (R16).
// One block per (b,q); 256 threads; thread t: j-group g = t>>7 (j=2*jj+g),
// head h = (t&127)>>3, dims d0 = (t&7)*8 (16 B).
// qkv: bf16 [B, S, 3, H, HD]. out: bf16 [B, S, H*HD].
__global__ __launch_bounds__(256) void attn_kernel(const unsigned short* __restrict__ qkv,
                                                   const int* __restrict__ routes,
                                                   unsigned short* __restrict__ out) {
    __shared__ float m_s[128], l_s[128];
    __shared__ float o_part[8][128];

    const int t  = threadIdx.x;           // 0..255
    const int id = blockIdx.x;
    // XCD-contiguity swizzle: same XCD (id%8) gets a contiguous bq range.
    const int bq = (id & 7) * 512 + (id >> 3);
    const int b  = bq >> 11;
    const int q  = bq & 2047;

    const int g  = t >> 7;                // j-group: 0 or 1
    const int th = t & 127;
    const int h  = th >> 3;               // head
    const int d0 = (t & 7) * 8;           // dim offset within head

    // Wave-uniform j-group for scalar addressing (readfirstlane hoists the
    // threadIdx-derived value into an SGPR so uniformity analysis succeeds).
    const int gs = __builtin_amdgcn_readfirstlane(g);

    // All 32 route indices for this wave -> SGPRs (uniform s_loads).
    int rr[32];
#pragma unroll
    for (int i = 0; i < 32; ++i) rr[i] = routes[q * KQ + i * 2 + gs];

    // q stays PACKED bf16 (4 uints = 8 elems); scale applied in exp2 arg.
    const uintx4 qp = *(const uintx4*)&qkv[((size_t)bq * 3) * DIMQ + h * HDQ + d0];

    // Uniform K/V row bases (scalar); per-lane element offset applied at load.
    const unsigned short* baseKu = qkv + ((size_t)b * SQ * 3 + 1) * DIMQ;
    const unsigned short* baseVu = qkv + ((size_t)b * SQ * 3 + 2) * DIMQ;
    const int laneoff = h * HDQ + d0;

    const float C = 0.18033688011112042f;   // SCALE * log2(e)
    float m = -1e30f, l = 0.f;
    float mC = 1e30f;                        // -m*C (cached for pe FMA)
    float m44 = -1e30f + 44.f;               // m+44 (cached for defer check)
    floatx2 o2[4];
#pragma unroll
    for (int i = 0; i < 4; ++i) o2[i] = (floatx2)(0.f);

    // Prefetch pipeline: 4 slots, loads for iteration jj+4 issued during jj.
    uintx4 kb[4], vb[4];
#pragma unroll
    for (int i = 0; i < 4; ++i) {
        const unsigned short* kp = baseKu + (size_t)rr[i] * QKV_STRIDE;
        const unsigned short* vp = baseVu + (size_t)rr[i] * QKV_STRIDE;
        kb[i] = *(const uintx4*)(kp + laneoff);
        vb[i] = *(const uintx4*)(vp + laneoff);
    }

#pragma unroll
    for (int jj = 0; jj < 32; ++jj) {
        const int slot = jj & 3;
        const uintx4 k4 = kb[slot];
        const uintx4 v4 = vb[slot];
        if (jj + 4 < 32) {
            const unsigned short* kp = baseKu + (size_t)rr[jj + 4] * QKV_STRIDE;
            const unsigned short* vp = baseVu + (size_t)rr[jj + 4] * QKV_STRIDE;
            kb[slot] = *(const uintx4*)(kp + laneoff);
            vb[slot] = *(const uintx4*)(vp + laneoff);
        }
        // QK dot: 4x v_dot2_f32_bf16 on packed bf16 pairs (no unpack).
        float p = 0.f;
#pragma unroll
        for (int i = 0; i < 4; ++i)
            asm("v_dot2_f32_bf16 %0, %1, %2, %0" : "+v"(p) : "v"(qp[i]), "v"(k4[i]));
        p += __shfl_xor(p, 1, 64);
        p += __shfl_xor(p, 2, 64);
        p += __shfl_xor(p, 4, 64);
        // Defer-max: rescale only when some lane's raw score jumps past m+44
        // (44 raw units * C = ~8 in exp2 domain -> pe <= 2^8).
        if (__any(p > m44)) {
            const float mn = fmaxf(m, p);       // per-lane guard -> exact
            const float al = exp2f((m - mn) * C);
            l *= al;
            const floatx2 al2 = { al, al };
#pragma unroll
            for (int i = 0; i < 4; ++i) o2[i] *= al2;
            m = mn;
            mC = -mn * C;
            m44 = mn + 44.f;
        }
        const float pe = exp2f(__builtin_fmaf(p, C, mC));   // <= 2^8
        l += pe;
        // PV: unpack bf16 pair (shift + and) then packed f32 FMA.
        const floatx2 pe2 = { pe, pe };
#pragma unroll
        for (int i = 0; i < 4; ++i) {
            const unsigned int u = v4[i];
            floatx2 vv;
            vv.x = u2f(u << 16);
            vv.y = u2f(u & 0xffff0000u);
            o2[i] += pe2 * vv;
        }
    }

    // Merge the two j-groups (softmax state merge, exp2 domain), then store.
    if (g == 1) {
        m_s[th] = m; l_s[th] = l;
#pragma unroll
        for (int i = 0; i < 4; ++i) {
            o_part[2 * i][th]     = o2[i].x;
            o_part[2 * i + 1][th] = o2[i].y;
        }
    }
    __syncthreads();
    if (g == 0) {
        const float m1 = m_s[th], l1m = l_s[th];
        const float mm = fmaxf(m, m1);
        const float a0 = exp2f((m - mm) * C);
        const float a1 = exp2f((m1 - mm) * C);
        const float inv = 1.0f / (l * a0 + l1m * a1);
        float oo[8];
#pragma unroll
        for (int i = 0; i < 4; ++i) {
            oo[2 * i]     = (o2[i].x * a0 + o_part[2 * i][th] * a1) * inv;
            oo[2 * i + 1] = (o2[i].y * a0 + o_part[2 * i + 1][th] * a1) * inv;
        }
        ushort4 lo, hi;
        lo.x = f2b(oo[0]); lo.y = f2b(oo[1]); lo.z = f2b(oo[2]); lo.w = f2b(oo[3]);
        hi.x = f2b(oo[4]); hi.y = f2b(oo[5]); hi.z = f2b(oo[6]); hi.w = f2b(oo[7]);
        ushort4* dst = (ushort4*)&out[(size_t)bq * DIMQ + h * HDQ + d0];
        dst[0] = lo; dst[1] = hi;
    }
}

// ---------------------------------------------------------------------------
extern "C" void kernel_launch(void* const* d_in, const int* in_sizes, int n_in,
                              void* d_out, int out_size, void* d_ws, size_t ws_size,
                              hipStream_t stream) {
    const float* x      = (const float*)d_in[0];
    const float* w_qkv  = (const float*)d_in[1];
    const float* b_qkv  = (const float*)d_in[2];
    const float* w_out  = (const float*)d_in[3];
    const float* b_out  = (const float*)d_in[4];
    const int*   routes = (const int*)d_in[5];
    float* out = (float*)d_out;

    // ws layout (bytes): [0,24M) qkv bf16 | [24M,..) xb / attnb (aliased)
    //                    then w_qkv_bf16, w_out_bf16
    char* ws = (char*)d_ws;
    unsigned short* qkvb  = (unsigned short*)ws;                      // 24 MB
    unsigned short* xb    = (unsigned short*)(ws + 25165824);         // 8.4 MB
    unsigned short* attnb = xb;                                       // aliased
    unsigned short* wqb   = (unsigned short*)(ws + 33554432);         // 6.3 MB
    unsigned short* wob   = (unsigned short*)(ws + 39845888);         // 2.1 MB

    const int M = BQ * SQ;   // 4096
    dim3 blk(256);

    // Fused casts (x, w_qkv, w_out), float4 per thread
    {
        const int n0 = M * DIMQ / 4, n1 = 3 * DIMQ * DIMQ / 4, n2 = DIMQ * DIMQ / 4;
        cast3_f32_bf16<<<(n0 + n1 + n2 + 255) / 256, blk, 0, stream>>>(
            x, xb, n0, w_qkv, wqb, n1, w_out, wob, n2);
    }

    // 1) QKV projection -> bf16 qkv [B,S,3,H,HD]  (768 blocks = 3/CU, T1 ok)
    gemm_bf16_nt<128, 128, unsigned short><<<dim3(3 * DIMQ / 128, M / 128), blk, 0, stream>>>(
        xb, wqb, b_qkv, qkvb, M, 3 * DIMQ, DIMQ);

    // 2) Routed attention: scalar-pipe addressing + defer-max + hw dot
    attn_kernel<<<BQ * SQ, blk, 0, stream>>>(qkvb, routes, attnb);

    // 3) Output projection -> fp32 final output (512 blocks = 2/CU, T1 ok)
    gemm_bf16_nt<128, 64, float><<<dim3(DIMQ / 64, M / 128), blk, 0, stream>>>(
        attnb, wob, b_out, out, M, DIMQ, DIMQ);
}